// Round 11
// baseline (948.671 us; speedup 1.0000x reference)
//
#include <hip/hip_runtime.h>

// ---------------- types & helpers ----------------
typedef __bf16 bf16x8 __attribute__((ext_vector_type(8)));
typedef float f32x4 __attribute__((ext_vector_type(4)));
typedef float f32x2 __attribute__((ext_vector_type(2)));
typedef unsigned short ushort4v __attribute__((ext_vector_type(4)));
typedef unsigned short ushort8v __attribute__((ext_vector_type(8)));

__device__ __forceinline__ unsigned short f2b(float f) {
  unsigned u = __float_as_uint(f);
  unsigned r = u + 0x7FFFu + ((u >> 16) & 1u);
  return (unsigned short)(r >> 16);
}
__device__ __forceinline__ float b2f(unsigned short v) {
  return __uint_as_float(((unsigned)v) << 16);
}

// ---- OCP e4m3 helpers (gfx950 HW cvt interprets fp8 as OCP) ----
__device__ __forceinline__ void fp8x4_to_f32(unsigned w, float out[4]) {
#if __has_builtin(__builtin_amdgcn_cvt_pk_f32_fp8)
  f32x2 lo = __builtin_amdgcn_cvt_pk_f32_fp8(w, false);
  f32x2 hi = __builtin_amdgcn_cvt_pk_f32_fp8(w, true);
  out[0] = lo[0]; out[1] = lo[1]; out[2] = hi[0]; out[3] = hi[1];
#else
#pragma unroll
  for (int i = 0; i < 4; ++i) {
    unsigned u = (w >> (8 * i)) & 0xffu;
    unsigned em = u & 0x7fu;
    float nrm = __uint_as_float((em + 960u) << 20);  // (e+120)<<23 | m<<20
    float sub = (float)em * 0x1p-9f;
    float mag = (em >= 8u) ? nrm : sub;
    out[i] = (u & 0x80u) ? -mag : mag;
  }
#endif
}

// software RTN encode f32 -> OCP e4m3 (cold path: GEMM epilogue only)
__device__ __forceinline__ unsigned char f32_to_fp8(float f) {
  float a = fabsf(f);
  unsigned s = (__float_as_uint(f) >> 31) << 7;
  a = fminf(a, 448.0f);
  unsigned r;
  if (a >= 0x1p-6f) {  // normal range
    unsigned b = __float_as_uint(a);
    unsigned m = b & 0x7fffffu;
    int ei = (int)(b >> 23) - 127;
    unsigned mr = (m + 0x80000u) >> 20;          // round mantissa to 3 bits (+carry)
    unsigned ee = (unsigned)(ei + 7) + (mr >> 3);
    mr &= 7u;
    if (ee >= 16u) { ee = 15u; mr = 6u; }        // clamp to 448 (0x7E), avoid NaN
    r = (ee << 3) | mr;
  } else {             // subnormal / zero: round(a*2^9); m==8 lands on first normal
    unsigned m = (unsigned)(a * 512.0f + 0.5f);
    r = m;
  }
  return (unsigned char)(s | r);
}

// ---------------- bucketed CSR build constants ----------------
static constexpr int BUCKET_NODES = 128;   // nodes per bucket (dlocal fits 7 bits)
static constexpr int BUCKET_CAP = 4096;    // 2x expected edges/bucket (~2046) — >20 sigma

// ---------------- small prep kernels ----------------
__global__ void k_bnprep(const float* __restrict__ g, const float* __restrict__ beta,
                         const float* __restrict__ rm, const float* __restrict__ rv,
                         const float* __restrict__ b, int n,
                         float* __restrict__ scale, float* __restrict__ shift) {
  int i = blockIdx.x * blockDim.x + threadIdx.x;
  if (i < n) {
    float s = g[i] * rsqrtf(rv[i] + 1e-5f);
    scale[i] = s;
    shift[i] = (b[i] - rm[i]) * s + beta[i];
  }
}

// W [K][N] f32 -> Wt [N][Kp] bf16 (zero-padded K..Kp)
__global__ void k_wt(const float* __restrict__ W, int K, int N, int Kp,
                     unsigned short* __restrict__ Wt) {
  int idx = blockIdx.x * blockDim.x + threadIdx.x;
  if (idx >= N * Kp) return;
  int n = idx / Kp, k = idx - n * Kp;
  Wt[idx] = f2b(k < K ? W[(size_t)k * N + n] : 0.0f);
}

// x f32 [n][74] -> xb bf16 [n][80], PRE-SCALED by dinv[row] (norm folding)
__global__ void k_x2b(const float* __restrict__ x, const float* __restrict__ dinv, int n,
                      unsigned short* __restrict__ xb) {
  int idx = blockIdx.x * blockDim.x + threadIdx.x;
  if (idx >= n * 20) return;
  int row = idx / 20, j = idx - row * 20;
  int f0 = j * 4;
  float dv = dinv[row];
  ushort4v o;
#pragma unroll
  for (int j2 = 0; j2 < 4; ++j2) {
    int f = f0 + j2;
    o[j2] = (f < 74) ? f2b(dv * x[(size_t)row * 74 + f]) : (unsigned short)0;
  }
  *(ushort4v*)(xb + (size_t)row * 80 + f0) = o;
}

// graph boundaries (batch sorted)
__global__ void k_gbounds(const int* __restrict__ batch, int n, int* __restrict__ gstart,
                          int* __restrict__ gend) {
  int i = blockIdx.x * blockDim.x + threadIdx.x;
  if (i >= n) return;
  int g = batch[i];
  if (i == 0 || batch[i - 1] != g) gstart[g] = i;
  if (i == n - 1 || batch[i + 1] != g) gend[g] = i + 1;
}

// ---------------- bucketed CSR build ----------------
// pass 1: append packed (dlocal<<17 | src) to dst-range buckets.
// Writes land on ~NB frontier lines -> full-line write combining.
__global__ void k_bucket(const int* __restrict__ src, const int* __restrict__ dst, int E,
                         int* __restrict__ bcur, unsigned* __restrict__ bdata) {
  int i = blockIdx.x * blockDim.x + threadIdx.x;
  if (i < E) {
    int d = dst[i];
    int b = d >> 7;            // / BUCKET_NODES
    int dl = d & 127;
    int pos = atomicAdd(&bcur[b], 1);
    if (pos < BUCKET_CAP)
      bdata[(size_t)b * BUCKET_CAP + pos] = (unsigned)src[i] | ((unsigned)dl << 17);
  }
}

// exclusive scan over NB (<=1024) bucket totals -> bbase; rowptr[NN] = total
__global__ void k_scanb(const int* __restrict__ bcur, int NB, int* __restrict__ bbase,
                        int* __restrict__ rowptr, int NN) {
  __shared__ int s[1024];
  int t = threadIdx.x;
  int v = (t < NB) ? min(bcur[t], BUCKET_CAP) : 0;
  s[t] = v;
  __syncthreads();
  for (int o = 1; o < 1024; o <<= 1) {
    int x = (t >= o) ? s[t - o] : 0;
    __syncthreads();
    s[t] += x;
    __syncthreads();
  }
  if (t < NB) bbase[t] = s[t] - v;  // exclusive
  if (t == 0) rowptr[NN] = s[1023];
}

// per-bucket: LDS count -> LDS scan -> rowptr/dinv (coalesced) -> local scatter
__global__ __launch_bounds__(256) void k_bucket_csr(const unsigned* __restrict__ bdata,
                                                    const int* __restrict__ bcur,
                                                    const int* __restrict__ bbase, int NN,
                                                    int* __restrict__ rowptr,
                                                    float* __restrict__ dinv,
                                                    int* __restrict__ colA) {
  __shared__ int lcnt[BUCKET_NODES];
  __shared__ int lpre[BUCKET_NODES];
  __shared__ int lcur[BUCKET_NODES];
  int b = blockIdx.x;
  int t = threadIdx.x;
  int n0 = b * BUCKET_NODES;
  int ne = min(bcur[b], BUCKET_CAP);
  const unsigned* bd = bdata + (size_t)b * BUCKET_CAP;
  if (t < BUCKET_NODES) lcnt[t] = 0;
  __syncthreads();
  for (int i = t; i < ne; i += 256) atomicAdd(&lcnt[bd[i] >> 17], 1);
  __syncthreads();
  // Hillis-Steele inclusive scan over 128, then convert to exclusive
  if (t < BUCKET_NODES) lpre[t] = lcnt[t];
  __syncthreads();
#pragma unroll
  for (int o = 1; o < BUCKET_NODES; o <<= 1) {
    int x = (t < BUCKET_NODES && t >= o) ? lpre[t - o] : 0;
    __syncthreads();
    if (t < BUCKET_NODES) lpre[t] += x;
    __syncthreads();
  }
  int base = bbase[b];
  if (t < BUCKET_NODES) {
    lpre[t] -= lcnt[t];  // exclusive
    int node = n0 + t;
    if (node < NN) {
      rowptr[node] = base + lpre[t];
      dinv[node] = rsqrtf(1.0f + (float)lcnt[t]);
    }
    lcur[t] = 0;
  }
  __syncthreads();
  for (int i = t; i < ne; i += 256) {
    unsigned pk = bd[i];
    int dl = pk >> 17;
    int slot = base + lpre[dl] + atomicAdd(&lcur[dl], 1);
    colA[slot] = (int)(pk & 0x1FFFFu);  // writes confined to this bucket's window
  }
}

// ---------------- aggregation ----------------
// layer 1: xb bf16 [n][80] (pre-scaled) -> agg bf16 [n][128].
// One wave per node; each HALF-wave (lanes 0-19) gathers edges; pure sums.
__global__ __launch_bounds__(256) void k_aggregate74b(const unsigned short* __restrict__ xb,
                                                      const int* __restrict__ rowptr,
                                                      const int* __restrict__ colA,
                                                      const float* __restrict__ dinv, int n,
                                                      unsigned short* __restrict__ out) {
  int wid = (int)((blockIdx.x * (size_t)blockDim.x + threadIdx.x) >> 6);
  int lane = threadIdx.x & 63;
  if (wid >= n) return;
  int half = lane >> 5, hl = lane & 31;
  bool act = hl < 20;
  float acc[4] = {0.0f, 0.0f, 0.0f, 0.0f};
  int e0 = rowptr[wid], e1 = rowptr[wid + 1];
  int e = e0;
  for (; e + 7 < e1; e += 8) {
    int b = e + half * 4;
    int s0 = colA[b], s1 = colA[b + 1], s2 = colA[b + 2], s3 = colA[b + 3];
    ushort4v v0 = {}, v1 = {}, v2 = {}, v3 = {};
    if (act) {
      v0 = *(const ushort4v*)(xb + (size_t)s0 * 80 + hl * 4);
      v1 = *(const ushort4v*)(xb + (size_t)s1 * 80 + hl * 4);
      v2 = *(const ushort4v*)(xb + (size_t)s2 * 80 + hl * 4);
      v3 = *(const ushort4v*)(xb + (size_t)s3 * 80 + hl * 4);
    }
#pragma unroll
    for (int j = 0; j < 4; ++j)
      acc[j] += (b2f(v0[j]) + b2f(v1[j])) + (b2f(v2[j]) + b2f(v3[j]));
  }
  for (int t = e + half; t < e1; t += 2) {
    int s = colA[t];
    ushort4v v = {};
    if (act) v = *(const ushort4v*)(xb + (size_t)s * 80 + hl * 4);
#pragma unroll
    for (int j = 0; j < 4; ++j) acc[j] += b2f(v[j]);
  }
  // combine the two halves (all 64 lanes participate)
#pragma unroll
  for (int j = 0; j < 4; ++j) acc[j] += __shfl_xor(acc[j], 32);
  if (half == 0) {
    float di = dinv[wid];
    if (act) {
      ushort4v sv = *(const ushort4v*)(xb + (size_t)wid * 80 + hl * 4);  // self (pre-scaled)
      ushort4v o;
#pragma unroll
      for (int j = 0; j < 4; ++j) o[j] = f2b(di * (acc[j] + b2f(sv[j])));
      *(ushort4v*)(out + (size_t)wid * 128 + hl * 4) = o;
    } else {
      ushort4v z = {};
      *(ushort4v*)(out + (size_t)wid * 128 + 80 + (hl - 20) * 4) = z;  // zero 80..127
    }
  }
}

// F=256: h' fp8 e4m3 in (pre-scaled by dinv), bf16 agg out. 4B/lane gathers.
__global__ __launch_bounds__(256) void k_aggregate256(const unsigned char* __restrict__ h8,
                                                      const int* __restrict__ rowptr,
                                                      const int* __restrict__ colA,
                                                      const float* __restrict__ dinv, int n,
                                                      unsigned short* __restrict__ out) {
  int wid = (int)((blockIdx.x * (size_t)blockDim.x + threadIdx.x) >> 6);
  int lane = threadIdx.x & 63;
  if (wid >= n) return;
  float acc[4];
  {
    unsigned w = *(const unsigned*)(h8 + (size_t)wid * 256 + lane * 4);  // self term
    fp8x4_to_f32(w, acc);
  }
  int e0 = rowptr[wid], e1 = rowptr[wid + 1];
  int e = e0;
  for (; e + 7 < e1; e += 8) {
    int c[8];
    unsigned w[8];
#pragma unroll
    for (int q = 0; q < 8; ++q) c[q] = colA[e + q];
#pragma unroll
    for (int q = 0; q < 8; ++q)
      w[q] = *(const unsigned*)(h8 + (size_t)c[q] * 256 + lane * 4);
#pragma unroll
    for (int q = 0; q < 8; ++q) {
      float v[4];
      fp8x4_to_f32(w[q], v);
#pragma unroll
      for (int j = 0; j < 4; ++j) acc[j] += v[j];
    }
  }
  for (; e < e1; ++e) {
    unsigned w = *(const unsigned*)(h8 + (size_t)colA[e] * 256 + lane * 4);
    float v[4];
    fp8x4_to_f32(w, v);
#pragma unroll
    for (int j = 0; j < 4; ++j) acc[j] += v[j];
  }
  float di = dinv[wid];
  ushort4v o;
#pragma unroll
  for (int j = 0; j < 4; ++j) o[j] = f2b(di * acc[j]);
  *(ushort4v*)(out + (size_t)wid * 256 + lane * 4) = o;
}

// ---------------- bf16 MFMA GEMM ----------------
// A [M][K] bf16, Bt [N][K] bf16. 128x64 tile, 4 waves 2x2, mfma 16x16x32.
// EPI 0: fp8(dinv[row]*relu(v*scale+shift)) -> C8 ; EPI 1: bf16(v+shift) -> C16
template <int EPI>
__global__ __launch_bounds__(256) void k_gemm_mfma(const unsigned short* __restrict__ A,
                                                   const unsigned short* __restrict__ Bt,
                                                   int M, int N, int K,
                                                   const float* __restrict__ scale,
                                                   const float* __restrict__ shift,
                                                   const float* __restrict__ dinv,
                                                   unsigned char* __restrict__ C8,
                                                   unsigned short* __restrict__ C16) {
  __shared__ __align__(16) unsigned short Ast[128 * 64];
  __shared__ __align__(16) unsigned short Bst[64 * 64];
  const int t = threadIdx.x;
  const int lane = t & 63;
  const int wid = t >> 6;
  const int wm = wid >> 1, wn = wid & 1;
  const int lr = lane >> 4, lc = lane & 15;
  const int m0 = blockIdx.y * 128;
  const int n0 = blockIdx.x * 64;
  f32x4 acc[4][2] = {};
  char* astB = (char*)Ast;
  char* bstB = (char*)Bst;

  for (int kb = 0; kb < K; kb += 64) {
#pragma unroll
    for (int i = 0; i < 4; ++i) {
      int c = t + 256 * i;
      int row = c >> 3, slot = c & 7;
      int gm = m0 + row;
      ushort8v v = {};
      if (gm < M) v = *(const ushort8v*)(A + (size_t)gm * K + kb + slot * 8);
      int byte = row * 128 + slot * 16;
      *(ushort8v*)(astB + (byte ^ ((row & 7) << 4))) = v;
    }
#pragma unroll
    for (int i = 0; i < 2; ++i) {
      int c = t + 256 * i;
      int row = c >> 3, slot = c & 7;
      ushort8v v = *(const ushort8v*)(Bt + (size_t)(n0 + row) * K + kb + slot * 8);
      int byte = row * 128 + slot * 16;
      *(ushort8v*)(bstB + (byte ^ ((row & 7) << 4))) = v;
    }
    __syncthreads();
#pragma unroll
    for (int kk = 0; kk < 2; ++kk) {
      bf16x8 a[4], b[2];
      int kbyte = lr * 16 + kk * 64;
#pragma unroll
      for (int mi = 0; mi < 4; ++mi) {
        int row = wm * 64 + mi * 16 + lc;
        int byte = row * 128 + kbyte;
        a[mi] = *(const bf16x8*)(astB + (byte ^ ((row & 7) << 4)));
      }
#pragma unroll
      for (int ni = 0; ni < 2; ++ni) {
        int row = wn * 32 + ni * 16 + lc;
        int byte = row * 128 + kbyte;
        b[ni] = *(const bf16x8*)(bstB + (byte ^ ((row & 7) << 4)));
      }
#pragma unroll
      for (int mi = 0; mi < 4; ++mi)
#pragma unroll
        for (int ni = 0; ni < 2; ++ni)
          acc[mi][ni] =
              __builtin_amdgcn_mfma_f32_16x16x32_bf16(a[mi], b[ni], acc[mi][ni], 0, 0, 0);
    }
    __syncthreads();
  }

  // epilogue: D row=(lane>>4)*4+reg, col=lane&15
#pragma unroll
  for (int ni = 0; ni < 2; ++ni) {
    int colx = n0 + wn * 32 + ni * 16 + lc;
    float sc = (EPI == 0) ? scale[colx] : 0.0f;
    float sh = shift[colx];
#pragma unroll
    for (int mi = 0; mi < 4; ++mi) {
      int rbase = m0 + wm * 64 + mi * 16 + lr * 4;
#pragma unroll
      for (int r = 0; r < 4; ++r) {
        int row = rbase + r;
        if (row < M) {
          float v = acc[mi][ni][r];
          if (EPI == 0) {
            v = fmaxf(fmaf(v, sc, sh), 0.0f) * dinv[row];
            C8[(size_t)row * N + colx] = f32_to_fp8(v);
          } else {
            v += sh;
            C16[(size_t)row * N + colx] = f2b(v);
          }
        }
      }
    }
  }
}

// ---------------- pooling: one block per graph, no atomics ----------------
__global__ __launch_bounds__(384) void k_pool(const unsigned short* __restrict__ h3,
                                              const int* __restrict__ gstart,
                                              const int* __restrict__ gend, int NF,
                                              float* __restrict__ out) {
  int g = blockIdx.x;
  int t = threadIdx.x;  // 0..383, one column each
  int s = gstart[g], e = gend[g];
  if (s >= 0 && e > s) {
    float sum = 0.0f, mx = -3.4e38f;
    for (int r = s; r < e; ++r) {
      float v = b2f(h3[(size_t)r * NF + t]);
      sum += v;
      mx = fmaxf(mx, v);
    }
    out[(size_t)g * NF + t] = sum / (float)(e - s) + mx;
  } else {
    out[(size_t)g * NF + t] = -INFINITY;
  }
}

// ---------------- host launch ----------------
extern "C" void kernel_launch(void* const* d_in, const int* in_sizes, int n_in, void* d_out,
                              int out_size, void* d_ws, size_t ws_size, hipStream_t stream) {
  const float* x    = (const float*)d_in[0];
  const int* edge   = (const int*)d_in[1];
  const int* batch  = (const int*)d_in[2];
  const float* W1   = (const float*)d_in[3];
  const float* b1   = (const float*)d_in[4];
  const float* g1   = (const float*)d_in[5];
  const float* be1  = (const float*)d_in[6];
  const float* rm1  = (const float*)d_in[7];
  const float* rv1  = (const float*)d_in[8];
  const float* W2   = (const float*)d_in[9];
  const float* b2   = (const float*)d_in[10];
  const float* g2   = (const float*)d_in[11];
  const float* be2  = (const float*)d_in[12];
  const float* rm2  = (const float*)d_in[13];
  const float* rv2  = (const float*)d_in[14];
  const float* W3   = (const float*)d_in[15];
  const float* b3   = (const float*)d_in[16];

  const int NN = in_sizes[2];       // 100000
  const int E  = in_sizes[1] / 2;   // 1600000
  const int F1 = in_sizes[4];       // 256
  const int F3 = in_sizes[16];      // 384
  const int NG = out_size / F3;     // 2048
  const int K1p = 128;              // padded K for layer 1 (74 -> 128)
  const int NB = (NN + BUCKET_NODES - 1) / BUCKET_NODES;  // 782 (<=1024 for NN<2^17)
  const int* srcv = edge;
  const int* dstv = edge + E;

  char* p = (char*)d_ws;
  auto carve = [&](size_t bytes) -> char* {
    char* r = p;
    p += (bytes + 255) & ~(size_t)255;
    return r;
  };
  float* dinv           = (float*)carve((size_t)NN * 4);
  int* rowptr           = (int*)carve((size_t)(NN + 1) * 4);
  int* bcur             = (int*)carve((size_t)NB * 4);
  int* bbase            = (int*)carve((size_t)NB * 4);
  int* colA             = (int*)carve((size_t)E * 4);
  float* scale1         = (float*)carve((size_t)F1 * 4);
  float* shift1         = (float*)carve((size_t)F1 * 4);
  float* scale2         = (float*)carve((size_t)F1 * 4);
  float* shift2         = (float*)carve((size_t)F1 * 4);
  unsigned short* W1t   = (unsigned short*)carve((size_t)F1 * K1p * 2);
  unsigned short* W2t   = (unsigned short*)carve((size_t)F1 * F1 * 2);
  unsigned short* W3t   = (unsigned short*)carve((size_t)F3 * F1 * 2);
  int* gstart           = (int*)carve((size_t)NG * 4);
  int* gend             = (int*)carve((size_t)NG * 4);
  unsigned short* xb    = (unsigned short*)carve((size_t)NN * 80 * 2);
  unsigned char* h8     = (unsigned char*)carve((size_t)NN * F1);       // fp8 h'
  unsigned short* agg   = (unsigned short*)carve((size_t)NN * F1 * 2);  // bf16 GEMM A
  unsigned short* h3    = (unsigned short*)carve((size_t)NN * F3 * 2);
  // bdata aliases h3: consumed by k_bucket_csr long before h3's first write (layer 3)
  unsigned* bdata       = (unsigned*)h3;   // needs NB*BUCKET_CAP*4 = 12.8MB <= 76.8MB
  (void)ws_size; (void)n_in;

  // init
  hipMemsetAsync(bcur, 0, (size_t)NB * 4, stream);
  hipMemsetAsync(gstart, 0xFF, (size_t)NG * 4, stream);
  hipMemsetAsync(gend, 0, (size_t)NG * 4, stream);
  k_bnprep<<<1, 256, 0, stream>>>(g1, be1, rm1, rv1, b1, F1, scale1, shift1);
  k_bnprep<<<1, 256, 0, stream>>>(g2, be2, rm2, rv2, b2, F1, scale2, shift2);
  k_wt<<<(F1 * K1p + 255) / 256, 256, 0, stream>>>(W1, 74, F1, K1p, W1t);
  k_wt<<<(F1 * F1 + 255) / 256, 256, 0, stream>>>(W2, F1, F1, F1, W2t);
  k_wt<<<(F3 * F1 + 255) / 256, 256, 0, stream>>>(W3, F1, F3, F1, W3t);
  k_gbounds<<<(NN + 255) / 256, 256, 0, stream>>>(batch, NN, gstart, gend);

  // bucketed CSR build (also produces dinv)
  k_bucket<<<(E + 255) / 256, 256, 0, stream>>>(srcv, dstv, E, bcur, bdata);
  k_scanb<<<1, 1024, 0, stream>>>(bcur, NB, bbase, rowptr, NN);
  k_bucket_csr<<<NB, 256, 0, stream>>>(bdata, bcur, bbase, NN, rowptr, dinv, colA);

  // x -> bf16, pre-scaled by dinv (norm folding)
  k_x2b<<<(NN * 20 + 255) / 256, 256, 0, stream>>>(x, dinv, NN, xb);

  dim3 blk(256);
  int aggBlocks = (NN + 3) / 4;
  int gy = (NN + 127) / 128;

  // Layer 1: agg(xb') -> bf16 [NN][128]; GEMM + bn1 + relu + dinv-fold -> h8 (fp8)
  k_aggregate74b<<<aggBlocks, blk, 0, stream>>>(xb, rowptr, colA, dinv, NN, agg);
  {
    dim3 grid(F1 / 64, gy);
    k_gemm_mfma<0><<<grid, blk, 0, stream>>>(agg, W1t, NN, F1, K1p, scale1, shift1, dinv,
                                             h8, nullptr);
  }
  // Layer 2
  k_aggregate256<<<aggBlocks, blk, 0, stream>>>(h8, rowptr, colA, dinv, NN, agg);
  {
    dim3 grid(F1 / 64, gy);
    k_gemm_mfma<0><<<grid, blk, 0, stream>>>(agg, W2t, NN, F1, F1, scale2, shift2, dinv,
                                             h8, nullptr);
  }
  // Layer 3: agg -> GEMM + bias -> h3 bf16 (bdata dead by now); then per-graph pool
  k_aggregate256<<<aggBlocks, blk, 0, stream>>>(h8, rowptr, colA, dinv, NN, agg);
  {
    dim3 grid(F3 / 64, gy);
    k_gemm_mfma<1><<<grid, blk, 0, stream>>>(agg, W3t, NN, F3, F1, nullptr, b3, dinv,
                                             nullptr, h3);
  }
  k_pool<<<NG, 384, 0, stream>>>(h3, gstart, gend, F3, (float*)d_out);
}